// Round 17
// baseline (188.273 us; speedup 1.0000x reference)
//
#include <hip/hip_runtime.h>
#include <stdint.h>

#define B_ 128
#define N_ 512
#define I_ 256
#define M_ 32
#define D_ 16

typedef __attribute__((ext_vector_type(4))) float f32x4;
typedef __attribute__((ext_vector_type(4))) float float4v;
typedef __attribute__((ext_vector_type(8))) short short8;     // 8 bf16 MFMA frag
typedef __attribute__((ext_vector_type(2))) unsigned int u32x2;
typedef __attribute__((ext_vector_type(4))) unsigned int u32x4;
typedef __attribute__((ext_vector_type(4))) unsigned short ushort4v;
typedef unsigned short ushort;

__device__ __forceinline__ float bf2f(ushort u) {
    union { unsigned int i; float f; } v; v.i = ((unsigned int)u) << 16; return v.f;
}
__device__ __forceinline__ ushort f2bf(float f) {
    union { float f; unsigned int i; } v; v.f = f;
    unsigned int r = v.i + 0x7FFFu + ((v.i >> 16) & 1u);   // RNE
    return (ushort)(r >> 16);
}

__device__ __forceinline__ u32x2 cvt4(float4v v) {
    unsigned int u0, u1;
    asm("v_cvt_pk_bf16_f32 %0, %1, %2" : "=v"(u0) : "v"(v[0]), "v"(v[1]));
    asm("v_cvt_pk_bf16_f32 %0, %1, %2" : "=v"(u1) : "v"(v[2]), "v"(v[3]));
    u32x2 r = {u0, u1};
    return r;
}

// volatile asm 16B load. RULE (r15): a VMW0() MUST sit between issue and ANY
// consume of the destination registers.
#define GL16(dst, ptr) \
    asm volatile("global_load_dwordx4 %0, %1, off" : "=&v"(dst) : "v"(ptr))

#define VMW0() do { \
    asm volatile("s_waitcnt vmcnt(0)" ::: "memory"); \
    __builtin_amdgcn_sched_barrier(0); \
} while (0)

// -----------------------------------------------------------------------------
// Kernel 0: x[b][n][i] fp32 -> xT[n][b][i] bf16 (32 MB, L3-resident).
// r9-proven coalesced streaming kernel.
// -----------------------------------------------------------------------------
__global__ __launch_bounds__(256) void conv_x(const float* __restrict__ x,
                                              ushort* __restrict__ xT) {
    const int rid = blockIdx.x * 4 + (threadIdx.x >> 6);   // rid = b*512 + n
    const int i0  = (threadIdx.x & 63) * 4;
    const int b   = rid >> 9;
    const int n   = rid & 511;
    float4v v = *(const float4v*)(x + (size_t)rid * I_ + i0);
    ushort4v h;
    h[0] = f2bf(v[0]); h[1] = f2bf(v[1]); h[2] = f2bf(v[2]); h[3] = f2bf(v[3]);
    *(ushort4v*)(xT + ((size_t)(n * B_ + b)) * I_ + i0) = h;
}

// -----------------------------------------------------------------------------
// Kernel 1: inputs_hat[b,m,n,d] = sum_i x[b,n,i] * W[m,n,d,i]
// SEQUENTIAL-W structure (r16 lesson: per-instr coalescing insufficient; DRAM
// granularity demands contiguous per-block streams). Block = (mq: 4 m's,
// nc: 16 consecutive n) -> W footprint = 4 x 256KB contiguous streams, read
// once. xT re-read (8x) served by L3. Per n: A-slice xT[n] (64KB, 64
// contiguous 1KB runs, no cvt) + W slab (64KB fp32, 1KB runs) -> LDS
// (r16-verified swizzle), A-frags in 32 VGPRs reused across 4 m's.
// -----------------------------------------------------------------------------
__global__ __launch_bounds__(512, 1) void hat_gemm(const float* __restrict__ W,
                                                   const ushort* __restrict__ xT,
                                                   ushort* __restrict__ hat) {
    __shared__ ushort LDSa[32768];   // 64 KB: A-slice [128 b][256 i] swizzled
    __shared__ ushort LDSw[16384];   // 32 KB: W slab [64 (ml,d)][256 i] swizzled

    const int bid  = blockIdx.x;     // 0..255
    const int xcd  = bid & 7;
    const int idx  = bid >> 3;       // 0..31
    const int nc   = xcd * 4 + (idx & 3);   // 0..31: all 8 mq of one nc on one XCD
    const int mq   = idx >> 2;       // 0..7

    const int tid  = threadIdx.x;    // 0..511
    const int lane = tid & 63;
    const int w    = tid >> 6;       // wave 0..7; owns b-rows [w*16, w*16+16)
    const int l15  = lane & 15;
    const int kq   = lane >> 4;      // 0..3

    short8  sva[8];                  // A staging (2 rows per GL16)
    float4v svw[8];                  // W staging (1 row per GL16)

    const int rowAl = (lane >> 5);          // 0/1: which of the 2 rows
    const int gA    = lane & 31;            // granule within 512B row

    #define ISSUE_A(n) do { \
        const ushort* xTn = xT + (size_t)(n) * (B_ * I_) + (size_t)(w * 16) * I_ + lane * 8; \
        _Pragma("unroll") \
        for (int j = 0; j < 8; ++j) GL16(sva[j], xTn + (size_t)j * 2 * I_); \
    } while (0)

    #define ISSUE_W(n) do { \
        _Pragma("unroll") \
        for (int u = 0; u < 8; ++u) { \
            const int rr = w * 8 + u; \
            const float* wp = W + ((((size_t)(mq * 4 + (rr >> 4))) * N_ + (n)) * D_ + (rr & 15)) * I_ + lane * 4; \
            GL16(svw[u], wp); \
        } \
    } while (0)

    #define WRITE_AW() do { \
        _Pragma("unroll") \
        for (int j = 0; j < 8; ++j) { \
            const int rowA = w * 16 + j * 2 + rowAl; \
            *(short8*)&LDSa[rowA * 256 + ((gA ^ (rowA & 15)) * 8)] = sva[j]; \
        } \
        _Pragma("unroll") \
        for (int u = 0; u < 8; ++u) { \
            const int rr = w * 8 + u; \
            u32x2 h = cvt4(svw[u]); \
            *(u32x2*)&LDSw[rr * 256 + (((lane >> 1) ^ (rr & 15)) * 8) + (lane & 1) * 4] = h; \
        } \
    } while (0)

    ISSUE_A(nc * 16); ISSUE_W(nc * 16);

    for (int ni = 0; ni < 16; ++ni) {
        const int n = nc * 16 + ni;

        VMW0();                      // this n's 16 loads landed (r15 rule)
        WRITE_AW();
        __syncthreads();             // LDS visible

        if (ni < 15) { ISSUE_A(n + 1); ISSUE_W(n + 1); }   // hide under compute

        // A-frags: row = w*16 + l15, granule = ks*4+kq, swizzle ^l15
        short8 afr[8];
        #pragma unroll
        for (int ks = 0; ks < 8; ++ks)
            afr[ks] = *(const short8*)&LDSa[(w * 16 + l15) * 256 + (((ks * 4 + kq) ^ l15) * 8)];

        #pragma unroll
        for (int ml = 0; ml < 4; ++ml) {
            f32x4 acc = {0.f, 0.f, 0.f, 0.f};
            #pragma unroll
            for (int ks = 0; ks < 8; ++ks) {
                short8 bf = *(const short8*)&LDSw[(ml * 16 + l15) * 256 + (((ks * 4 + kq) ^ l15) * 8)];
                acc = __builtin_amdgcn_mfma_f32_16x16x32_bf16(afr[ks], bf, acc, 0, 0, 0);
            }
            // D map: col = lane&15 (=d), row = kq*4 + r (verified)
            const int m = mq * 4 + ml;
            #pragma unroll
            for (int r = 0; r < 4; ++r) {
                const int b = w * 16 + kq * 4 + r;
                hat[(((size_t)b * M_ + m) * N_ + n) * D_ + l15] = f2bf(acc[r]);
            }
        }
        __syncthreads();             // all LDS reads done before next WRITE
    }
    #undef ISSUE_A
    #undef ISSUE_W
    #undef WRITE_AW
}

// -----------------------------------------------------------------------------
// Kernel 2: dynamic routing (3 iterations), one block per batch element b.
// (r13/r16 version — known-correct, unchanged)
// -----------------------------------------------------------------------------
__global__ __launch_bounds__(512) void routing(const ushort* __restrict__ hat,
                                               float* __restrict__ out) {
    __shared__ float blog[M_][N_];
    __shared__ float cmax[N_];
    __shared__ float rcsum[N_];

    const int b    = blockIdx.x;
    const int tid  = threadIdx.x;
    const int lane = tid & 63;
    const int w    = tid >> 6;

    #pragma unroll
    for (int m = 0; m < M_; ++m) blog[m][tid] = 0.f;
    __syncthreads();

    float ov[4][16];
    typedef __attribute__((ext_vector_type(4))) float fl4;

    for (int it = 0; it < 3; ++it) {
        {
            float mx = -3.4e38f;
            #pragma unroll
            for (int m = 0; m < M_; ++m) mx = fmaxf(mx, blog[m][tid]);
            float s = 0.f;
            #pragma unroll
            for (int m = 0; m < M_; ++m) s += __expf(blog[m][tid] - mx);
            cmax[tid]  = mx;
            rcsum[tid] = 1.f / s;
        }
        __syncthreads();

        float sacc[4][16];
        #pragma unroll
        for (int q = 0; q < 4; ++q)
            #pragma unroll
            for (int dd = 0; dd < 16; ++dd) sacc[q][dd] = 0.f;

        for (int r = 0; r < 8; ++r) {
            const int nn = r * 64 + lane;
            #pragma unroll
            for (int q = 0; q < 4; ++q) {
                const int m = w * 4 + q;
                const float cm = __expf(blog[m][nn] - cmax[nn]) * rcsum[nn];
                const size_t base = (((size_t)b * M_ + m) * N_ + nn) * D_;
                short8 h0 = *(const short8*)(hat + base);
                short8 h1 = *(const short8*)(hat + base + 8);
                #pragma unroll
                for (int dd = 0; dd < 8; ++dd) {
                    sacc[q][dd]     += cm * bf2f((ushort)h0[dd]);
                    sacc[q][8 + dd] += cm * bf2f((ushort)h1[dd]);
                }
            }
        }
        #pragma unroll
        for (int off = 32; off >= 1; off >>= 1) {
            #pragma unroll
            for (int q = 0; q < 4; ++q)
                #pragma unroll
                for (int dd = 0; dd < 16; ++dd)
                    sacc[q][dd] += __shfl_xor(sacc[q][dd], off, 64);
        }
        #pragma unroll
        for (int q = 0; q < 4; ++q) {
            float s2 = 0.f;
            #pragma unroll
            for (int dd = 0; dd < 16; ++dd) s2 += sacc[q][dd] * sacc[q][dd];
            const float scale = s2 / (1.f + s2) / sqrtf(s2 + 1e-7f);
            #pragma unroll
            for (int dd = 0; dd < 16; ++dd) ov[q][dd] = scale * sacc[q][dd];
        }

        if (it < 2) {
            for (int r = 0; r < 8; ++r) {
                const int nn = r * 64 + lane;
                #pragma unroll
                for (int q = 0; q < 4; ++q) {
                    const int m = w * 4 + q;
                    const size_t base = (((size_t)b * M_ + m) * N_ + nn) * D_;
                    short8 h0 = *(const short8*)(hat + base);
                    short8 h1 = *(const short8*)(hat + base + 8);
                    float dot = 0.f;
                    #pragma unroll
                    for (int dd = 0; dd < 8; ++dd) {
                        dot += ov[q][dd]     * bf2f((ushort)h0[dd]);
                        dot += ov[q][8 + dd] * bf2f((ushort)h1[dd]);
                    }
                    blog[m][nn] += dot;
                }
            }
        }
        __syncthreads();
    }

    if (lane == 0) {
        #pragma unroll
        for (int q = 0; q < 4; ++q) {
            const int m = w * 4 + q;
            #pragma unroll
            for (int c4 = 0; c4 < 4; ++c4) {
                fl4 v;
                v[0] = ov[q][c4 * 4 + 0];
                v[1] = ov[q][c4 * 4 + 1];
                v[2] = ov[q][c4 * 4 + 2];
                v[3] = ov[q][c4 * 4 + 3];
                *(fl4*)&out[((size_t)b * M_ + m) * D_ + c4 * 4] = v;
            }
        }
    }
}

extern "C" void kernel_launch(void* const* d_in, const int* in_sizes, int n_in,
                              void* d_out, int out_size, void* d_ws, size_t ws_size,
                              hipStream_t stream) {
    const float* x = (const float*)d_in[0];        // [128, 512, 256] fp32
    const float* W = (const float*)d_in[1];        // [32, 512, 16, 256] fp32
    ushort* hat = (ushort*)d_ws;                   // bf16 [128,32,512,16] = 64 MB
    ushort* xT  = (ushort*)((char*)d_ws + (size_t)64 * 1024 * 1024); // bf16 [512,128,256] = 32 MB
    float* out = (float*)d_out;                    // fp32 [128,32,16]

    conv_x<<<dim3((B_ * N_) / 4), dim3(256), 0, stream>>>(x, xT);
    hat_gemm<<<dim3(256), dim3(512), 0, stream>>>(W, xT, hat);
    routing<<<dim3(B_), dim3(512), 0, stream>>>(hat, out);
}

// Round 18
// 165.711 us; speedup vs baseline: 1.1362x; 1.1362x over previous
//
#include <hip/hip_runtime.h>
#include <stdint.h>

#define B_ 128
#define N_ 512
#define I_ 256
#define M_ 32
#define D_ 16

typedef __attribute__((ext_vector_type(4))) float f32x4;
typedef __attribute__((ext_vector_type(4))) float float4v;
typedef __attribute__((ext_vector_type(8))) short short8;     // 8 bf16 MFMA frag
typedef __attribute__((ext_vector_type(2))) unsigned int u32x2;
typedef __attribute__((ext_vector_type(4))) unsigned int u32x4;
typedef unsigned short ushort;

__device__ __forceinline__ float bf2f(ushort u) {
    union { unsigned int i; float f; } v; v.i = ((unsigned int)u) << 16; return v.f;
}
__device__ __forceinline__ ushort f2bf(float f) {
    union { float f; unsigned int i; } v; v.f = f;
    unsigned int r = v.i + 0x7FFFu + ((v.i >> 16) & 1u);   // RNE
    return (ushort)(r >> 16);
}

__device__ __forceinline__ short8 cvt8(float4v lo, float4v hi) {
    unsigned int u0, u1, u2, u3;
    asm("v_cvt_pk_bf16_f32 %0, %1, %2" : "=v"(u0) : "v"(lo[0]), "v"(lo[1]));
    asm("v_cvt_pk_bf16_f32 %0, %1, %2" : "=v"(u1) : "v"(lo[2]), "v"(lo[3]));
    asm("v_cvt_pk_bf16_f32 %0, %1, %2" : "=v"(u2) : "v"(hi[0]), "v"(hi[1]));
    asm("v_cvt_pk_bf16_f32 %0, %1, %2" : "=v"(u3) : "v"(hi[2]), "v"(hi[3]));
    u32x4 uv = {u0, u1, u2, u3};
    return __builtin_bit_cast(short8, uv);
}
__device__ __forceinline__ u32x2 cvt4(float4v v) {
    unsigned int u0, u1;
    asm("v_cvt_pk_bf16_f32 %0, %1, %2" : "=v"(u0) : "v"(v[0]), "v"(v[1]));
    asm("v_cvt_pk_bf16_f32 %0, %1, %2" : "=v"(u1) : "v"(v[2]), "v"(v[3]));
    u32x2 r = {u0, u1};
    return r;
}

// volatile asm 16B load with compile-time byte offset.
// RULE (r15): a VMW0() MUST sit between issue and ANY consume of the dest regs.
#define GL16(dst, base, imm) \
    asm volatile("global_load_dwordx4 %0, %1, off offset:%2" \
                 : "=&v"(dst) : "v"(base), "n"(imm))

#define VMW0() do { \
    asm volatile("s_waitcnt vmcnt(0)" ::: "memory"); \
    __builtin_amdgcn_sched_barrier(0); \
} while (0)

// -----------------------------------------------------------------------------
// Kernel 1: inputs_hat[b,m,n,d] = sum_i x[b,n,i] * W[m,n,d,i]
// BEST-MEASURED structure (161.3 us total, round-16 bench) — verbatim.
// Block per n (512, XCD-chunked), 8 waves, 64KB LDS, 2 blocks/CU.
//  phase 1: x[.][n] -> bf16 LDS (16B/lane coalesced, granule swizzle).
//  phase 2: wave's 16-row A-band -> 32 VGPRs (held for whole kernel).
//  phase 3: LDS reused as W double-buffer; 8 chunks x 4 m; 1KB-contiguous
//           W row loads; chunk c+1 issued before compute(c).
// -----------------------------------------------------------------------------
__global__ __launch_bounds__(512, 2) void hat_gemm(const float* __restrict__ x,
                                                   const float* __restrict__ W,
                                                   ushort* __restrict__ hat) {
    __shared__ ushort LDS[32768];   // 64 KB

    const int bid = blockIdx.x;     // 0..511
    const int n   = (bid & 7) * 64 + (bid >> 3);   // XCD-chunked n

    const int tid  = threadIdx.x;   // 0..511
    const int lane = tid & 63;
    const int w    = tid >> 6;      // wave 0..7; owns b-rows [w*16, w*16+16)
    const int l15  = lane & 15;
    const int kq   = lane >> 4;     // 0..3

    // ---- phase 1: stage x -> bf16 LDS ----
    {
        const int row = tid >> 2;       // b = 0..127
        const int seg = tid & 3;        // quarter-row (64 floats)
        const float* xp = x + ((size_t)row * N_ + n) * I_ + seg * 64;
        float4v sx[16];
        #pragma unroll
        for (int j = 0; j < 16; ++j) GL16(sx[j], xp, j * 16);
        VMW0();
        #pragma unroll
        for (int i = 0; i < 8; ++i) {
            short8 h = cvt8(sx[2 * i], sx[2 * i + 1]);
            const int gsw = (seg * 8 + i) ^ (row & 15);
            *(short8*)&LDS[row * 256 + gsw * 8] = h;
        }
    }
    __syncthreads();

    // ---- phase 2: A-band into registers ----
    short8 afr[8];
    #pragma unroll
    for (int ks = 0; ks < 8; ++ks)
        afr[ks] = *(const short8*)&LDS[(w * 16 + l15) * 256 + (((ks * 4 + kq) ^ l15) * 8)];

    float4v sv[8];      // W chunk staging (8 rows/wave, 1KB contiguous each)

    #define ISSUEW(c) do { \
        _Pragma("unroll") \
        for (int u = 0; u < 8; ++u) { \
            const int rr = w * 8 + u; \
            const int ml = rr >> 4, dd = rr & 15; \
            const float* wp = W + ((((size_t)((c) * 4 + ml)) * N_ + n) * D_ + dd) * I_ + lane * 4; \
            GL16(sv[u], wp, 0); \
        } \
    } while (0)

    #define WRITEW(c) do { \
        ushort* buf = &LDS[((c) & 1) * 16384]; \
        _Pragma("unroll") \
        for (int u = 0; u < 8; ++u) { \
            const int rr = w * 8 + u; \
            const int dd = rr & 15; \
            u32x2 h = cvt4(sv[u]); \
            *(u32x2*)&buf[rr * 256 + (((lane >> 1) ^ dd) * 8) + (lane & 1) * 4] = h; \
        } \
    } while (0)

    ISSUEW(0);
    __syncthreads();
    VMW0();
    WRITEW(0);
    __syncthreads();

    // ---- phase 3: 8 chunks of 4 m ----
    for (int c = 0; c < 8; ++c) {
        if (c < 7) ISSUEW(c + 1);
        const ushort* buf = &LDS[(c & 1) * 16384];
        #pragma unroll
        for (int mq = 0; mq < 4; ++mq) {
            const int m = c * 4 + mq;
            f32x4 acc = {0.f, 0.f, 0.f, 0.f};
            #pragma unroll
            for (int ks = 0; ks < 8; ++ks) {
                short8 bf = *(const short8*)&buf[(mq * 16 + l15) * 256 + (((ks * 4 + kq) ^ l15) * 8)];
                acc = __builtin_amdgcn_mfma_f32_16x16x32_bf16(afr[ks], bf, acc, 0, 0, 0);
            }
            #pragma unroll
            for (int r = 0; r < 4; ++r) {
                const int b = w * 16 + kq * 4 + r;
                hat[(((size_t)b * M_ + m) * N_ + n) * D_ + l15] = f2bf(acc[r]);
            }
        }
        if (c < 7) {
            VMW0();
            WRITEW(c + 1);
            __syncthreads();
        }
    }
    #undef ISSUEW
    #undef WRITEW
}

// -----------------------------------------------------------------------------
// Kernel 2: dynamic routing, FUSED 3-pass version (round-14-proven, verbatim).
// Pass 1: c = 1/32. Transitions t=0,1: one hat read serves BOTH the b-logit
// dot-update and the next iteration's c*hat accumulation (bitwise exact).
// -----------------------------------------------------------------------------
__global__ __launch_bounds__(512, 1) void routing(const ushort* __restrict__ hat,
                                                  float* __restrict__ out) {
    __shared__ float blog[M_][N_];      // 64 KB

    const int b    = blockIdx.x;
    const int tid  = threadIdx.x;
    const int lane = tid & 63;
    const int w    = tid >> 6;

    #pragma unroll
    for (int m = 0; m < M_; ++m) blog[m][tid] = 0.f;
    __syncthreads();

    float ov[4][16], sacc[4][16];
    typedef __attribute__((ext_vector_type(4))) float fl4;

    #define REDUCE_SQUASH() do { \
        _Pragma("unroll") \
        for (int off = 32; off >= 1; off >>= 1) { \
            _Pragma("unroll") \
            for (int q = 0; q < 4; ++q) \
                _Pragma("unroll") \
                for (int dd = 0; dd < 16; ++dd) \
                    sacc[q][dd] += __shfl_xor(sacc[q][dd], off, 64); \
        } \
        _Pragma("unroll") \
        for (int q = 0; q < 4; ++q) { \
            float s2 = 0.f; \
            _Pragma("unroll") \
            for (int dd = 0; dd < 16; ++dd) s2 += sacc[q][dd] * sacc[q][dd]; \
            const float scale = s2 / (1.f + s2) / sqrtf(s2 + 1e-7f); \
            _Pragma("unroll") \
            for (int dd = 0; dd < 16; ++dd) ov[q][dd] = scale * sacc[q][dd]; \
        } \
    } while (0)

    // pass 1: c = 1/32 (softmax of zeros)
    #pragma unroll
    for (int q = 0; q < 4; ++q)
        #pragma unroll
        for (int dd = 0; dd < 16; ++dd) sacc[q][dd] = 0.f;

    for (int r = 0; r < 8; ++r) {
        const int nn = r * 64 + lane;
        #pragma unroll
        for (int q = 0; q < 4; ++q) {
            const int m = w * 4 + q;
            const size_t base = (((size_t)b * M_ + m) * N_ + nn) * D_;
            short8 h0 = *(const short8*)(hat + base);
            short8 h1 = *(const short8*)(hat + base + 8);
            const float cm = 0.03125f;
            #pragma unroll
            for (int dd = 0; dd < 8; ++dd) {
                sacc[q][dd]     += cm * bf2f((ushort)h0[dd]);
                sacc[q][8 + dd] += cm * bf2f((ushort)h1[dd]);
            }
        }
    }
    REDUCE_SQUASH();

    // transitions t=0,1: fused dot -> blog -> softmax -> s accumulation
    for (int t = 0; t < 2; ++t) {
        #pragma unroll
        for (int q = 0; q < 4; ++q)
            #pragma unroll
            for (int dd = 0; dd < 16; ++dd) sacc[q][dd] = 0.f;

        for (int r = 0; r < 8; ++r) {
            const int nn = r * 64 + lane;
            short8 hh0[4], hh1[4];
            #pragma unroll
            for (int q = 0; q < 4; ++q) {
                const int m = w * 4 + q;
                const size_t base = (((size_t)b * M_ + m) * N_ + nn) * D_;
                hh0[q] = *(const short8*)(hat + base);
                hh1[q] = *(const short8*)(hat + base + 8);
                float dot = 0.f;
                #pragma unroll
                for (int dd = 0; dd < 8; ++dd) {
                    dot += ov[q][dd]     * bf2f((ushort)hh0[q][dd]);
                    dot += ov[q][8 + dd] * bf2f((ushort)hh1[q][dd]);
                }
                blog[m][nn] += dot;        // owner-exclusive RMW
            }
            __syncthreads();               // all m's logits for these nn final
            float mx = -3.4e38f;
            #pragma unroll
            for (int mm = 0; mm < M_; ++mm) mx = fmaxf(mx, blog[mm][nn]);
            float ss = 0.f;
            #pragma unroll
            for (int mm = 0; mm < M_; ++mm) ss += __expf(blog[mm][nn] - mx);
            const float rs = 1.f / ss;
            #pragma unroll
            for (int q = 0; q < 4; ++q) {
                const float cm = __expf(blog[w * 4 + q][nn] - mx) * rs;
                #pragma unroll
                for (int dd = 0; dd < 8; ++dd) {
                    sacc[q][dd]     += cm * bf2f((ushort)hh0[q][dd]);
                    sacc[q][8 + dd] += cm * bf2f((ushort)hh1[q][dd]);
                }
            }
        }
        REDUCE_SQUASH();
    }
    #undef REDUCE_SQUASH

    // ---- write final outputs [B, M, D] fp32 ----
    if (lane == 0) {
        #pragma unroll
        for (int q = 0; q < 4; ++q) {
            const int m = w * 4 + q;
            #pragma unroll
            for (int c4 = 0; c4 < 4; ++c4) {
                fl4 v;
                v[0] = ov[q][c4 * 4 + 0];
                v[1] = ov[q][c4 * 4 + 1];
                v[2] = ov[q][c4 * 4 + 2];
                v[3] = ov[q][c4 * 4 + 3];
                *(fl4*)&out[((size_t)b * M_ + m) * D_ + c4 * 4] = v;
            }
        }
    }
}

extern "C" void kernel_launch(void* const* d_in, const int* in_sizes, int n_in,
                              void* d_out, int out_size, void* d_ws, size_t ws_size,
                              hipStream_t stream) {
    const float* x = (const float*)d_in[0];        // [128, 512, 256] fp32
    const float* W = (const float*)d_in[1];        // [32, 512, 16, 256] fp32
    ushort* hat = (ushort*)d_ws;                   // bf16 [128,32,512,16] = 64 MB
    float* out = (float*)d_out;                    // fp32 [128,32,16]

    hat_gemm<<<dim3(N_), dim3(512), 0, stream>>>(x, W, hat);
    routing<<<dim3(B_), dim3(512), 0, stream>>>(hat, out);
}

// Round 19
// 160.889 us; speedup vs baseline: 1.1702x; 1.0300x over previous
//
#include <hip/hip_runtime.h>
#include <stdint.h>

#define B_ 128
#define N_ 512
#define I_ 256
#define M_ 32
#define D_ 16

typedef __attribute__((ext_vector_type(4))) float f32x4;
typedef __attribute__((ext_vector_type(4))) float float4v;
typedef __attribute__((ext_vector_type(8))) short short8;     // 8 bf16 MFMA frag
typedef __attribute__((ext_vector_type(2))) unsigned int u32x2;
typedef __attribute__((ext_vector_type(4))) unsigned int u32x4;
typedef unsigned short ushort;

__device__ __forceinline__ float bf2f(ushort u) {
    union { unsigned int i; float f; } v; v.i = ((unsigned int)u) << 16; return v.f;
}
__device__ __forceinline__ ushort f2bf(float f) {
    union { float f; unsigned int i; } v; v.f = f;
    unsigned int r = v.i + 0x7FFFu + ((v.i >> 16) & 1u);   // RNE
    return (ushort)(r >> 16);
}

__device__ __forceinline__ short8 cvt8(float4v lo, float4v hi) {
    unsigned int u0, u1, u2, u3;
    asm("v_cvt_pk_bf16_f32 %0, %1, %2" : "=v"(u0) : "v"(lo[0]), "v"(lo[1]));
    asm("v_cvt_pk_bf16_f32 %0, %1, %2" : "=v"(u1) : "v"(lo[2]), "v"(lo[3]));
    asm("v_cvt_pk_bf16_f32 %0, %1, %2" : "=v"(u2) : "v"(hi[0]), "v"(hi[1]));
    asm("v_cvt_pk_bf16_f32 %0, %1, %2" : "=v"(u3) : "v"(hi[2]), "v"(hi[3]));
    u32x4 uv = {u0, u1, u2, u3};
    return __builtin_bit_cast(short8, uv);
}
__device__ __forceinline__ u32x2 cvt4(float4v v) {
    unsigned int u0, u1;
    asm("v_cvt_pk_bf16_f32 %0, %1, %2" : "=v"(u0) : "v"(v[0]), "v"(v[1]));
    asm("v_cvt_pk_bf16_f32 %0, %1, %2" : "=v"(u1) : "v"(v[2]), "v"(v[3]));
    u32x2 r = {u0, u1};
    return r;
}

// volatile asm 16B load with compile-time byte offset.
// RULE (r15): a VMW0() MUST sit between issue and ANY consume of the dest regs.
#define GL16(dst, base, imm) \
    asm volatile("global_load_dwordx4 %0, %1, off offset:%2" \
                 : "=&v"(dst) : "v"(base), "n"(imm))

#define VMW0() do { \
    asm volatile("s_waitcnt vmcnt(0)" ::: "memory"); \
    __builtin_amdgcn_sched_barrier(0); \
} while (0)

// -----------------------------------------------------------------------------
// Kernel 1: inputs_hat[b,m,n,d] = sum_i x[b,n,i] * W[m,n,d,i]
// BEST-MEASURED structure (161.3 us total, round-16 bench) — verbatim.
// Block per n (512, XCD-chunked), 8 waves, 64KB LDS, 2 blocks/CU.
//  phase 1: x[.][n] -> bf16 LDS (16B/lane coalesced, granule swizzle).
//  phase 2: wave's 16-row A-band -> 32 VGPRs (held for whole kernel).
//  phase 3: LDS reused as W double-buffer; 8 chunks x 4 m; 1KB-contiguous
//           W row loads; chunk c+1 issued before compute(c).
// -----------------------------------------------------------------------------
__global__ __launch_bounds__(512, 2) void hat_gemm(const float* __restrict__ x,
                                                   const float* __restrict__ W,
                                                   ushort* __restrict__ hat) {
    __shared__ ushort LDS[32768];   // 64 KB

    const int bid = blockIdx.x;     // 0..511
    const int n   = (bid & 7) * 64 + (bid >> 3);   // XCD-chunked n

    const int tid  = threadIdx.x;   // 0..511
    const int lane = tid & 63;
    const int w    = tid >> 6;      // wave 0..7; owns b-rows [w*16, w*16+16)
    const int l15  = lane & 15;
    const int kq   = lane >> 4;     // 0..3

    // ---- phase 1: stage x -> bf16 LDS ----
    {
        const int row = tid >> 2;       // b = 0..127
        const int seg = tid & 3;        // quarter-row (64 floats)
        const float* xp = x + ((size_t)row * N_ + n) * I_ + seg * 64;
        float4v sx[16];
        #pragma unroll
        for (int j = 0; j < 16; ++j) GL16(sx[j], xp, j * 16);
        VMW0();
        #pragma unroll
        for (int i = 0; i < 8; ++i) {
            short8 h = cvt8(sx[2 * i], sx[2 * i + 1]);
            const int gsw = (seg * 8 + i) ^ (row & 15);
            *(short8*)&LDS[row * 256 + gsw * 8] = h;
        }
    }
    __syncthreads();

    // ---- phase 2: A-band into registers ----
    short8 afr[8];
    #pragma unroll
    for (int ks = 0; ks < 8; ++ks)
        afr[ks] = *(const short8*)&LDS[(w * 16 + l15) * 256 + (((ks * 4 + kq) ^ l15) * 8)];

    float4v sv[8];      // W chunk staging (8 rows/wave, 1KB contiguous each)

    #define ISSUEW(c) do { \
        _Pragma("unroll") \
        for (int u = 0; u < 8; ++u) { \
            const int rr = w * 8 + u; \
            const int ml = rr >> 4, dd = rr & 15; \
            const float* wp = W + ((((size_t)((c) * 4 + ml)) * N_ + n) * D_ + dd) * I_ + lane * 4; \
            GL16(sv[u], wp, 0); \
        } \
    } while (0)

    #define WRITEW(c) do { \
        ushort* buf = &LDS[((c) & 1) * 16384]; \
        _Pragma("unroll") \
        for (int u = 0; u < 8; ++u) { \
            const int rr = w * 8 + u; \
            const int dd = rr & 15; \
            u32x2 h = cvt4(sv[u]); \
            *(u32x2*)&buf[rr * 256 + (((lane >> 1) ^ dd) * 8) + (lane & 1) * 4] = h; \
        } \
    } while (0)

    ISSUEW(0);
    __syncthreads();
    VMW0();
    WRITEW(0);
    __syncthreads();

    // ---- phase 3: 8 chunks of 4 m ----
    for (int c = 0; c < 8; ++c) {
        if (c < 7) ISSUEW(c + 1);
        const ushort* buf = &LDS[(c & 1) * 16384];
        #pragma unroll
        for (int mq = 0; mq < 4; ++mq) {
            const int m = c * 4 + mq;
            f32x4 acc = {0.f, 0.f, 0.f, 0.f};
            #pragma unroll
            for (int ks = 0; ks < 8; ++ks) {
                short8 bf = *(const short8*)&buf[(mq * 16 + l15) * 256 + (((ks * 4 + kq) ^ l15) * 8)];
                acc = __builtin_amdgcn_mfma_f32_16x16x32_bf16(afr[ks], bf, acc, 0, 0, 0);
            }
            #pragma unroll
            for (int r = 0; r < 4; ++r) {
                const int b = w * 16 + kq * 4 + r;
                hat[(((size_t)b * M_ + m) * N_ + n) * D_ + l15] = f2bf(acc[r]);
            }
        }
        if (c < 7) {
            VMW0();
            WRITEW(c + 1);
            __syncthreads();
        }
    }
    #undef ISSUEW
    #undef WRITEW
}

// -----------------------------------------------------------------------------
// Kernel 2: dynamic routing (3 iterations), one block per batch element b.
// (unfused r13/r16 version — best-measured, verbatim)
// -----------------------------------------------------------------------------
__global__ __launch_bounds__(512) void routing(const ushort* __restrict__ hat,
                                               float* __restrict__ out) {
    __shared__ float blog[M_][N_];
    __shared__ float cmax[N_];
    __shared__ float rcsum[N_];

    const int b    = blockIdx.x;
    const int tid  = threadIdx.x;
    const int lane = tid & 63;
    const int w    = tid >> 6;

    #pragma unroll
    for (int m = 0; m < M_; ++m) blog[m][tid] = 0.f;
    __syncthreads();

    float ov[4][16];
    typedef __attribute__((ext_vector_type(4))) float fl4;

    for (int it = 0; it < 3; ++it) {
        {
            float mx = -3.4e38f;
            #pragma unroll
            for (int m = 0; m < M_; ++m) mx = fmaxf(mx, blog[m][tid]);
            float s = 0.f;
            #pragma unroll
            for (int m = 0; m < M_; ++m) s += __expf(blog[m][tid] - mx);
            cmax[tid]  = mx;
            rcsum[tid] = 1.f / s;
        }
        __syncthreads();

        float sacc[4][16];
        #pragma unroll
        for (int q = 0; q < 4; ++q)
            #pragma unroll
            for (int dd = 0; dd < 16; ++dd) sacc[q][dd] = 0.f;

        for (int r = 0; r < 8; ++r) {
            const int nn = r * 64 + lane;
            #pragma unroll
            for (int q = 0; q < 4; ++q) {
                const int m = w * 4 + q;
                const float cm = __expf(blog[m][nn] - cmax[nn]) * rcsum[nn];
                const size_t base = (((size_t)b * M_ + m) * N_ + nn) * D_;
                short8 h0 = *(const short8*)(hat + base);
                short8 h1 = *(const short8*)(hat + base + 8);
                #pragma unroll
                for (int dd = 0; dd < 8; ++dd) {
                    sacc[q][dd]     += cm * bf2f((ushort)h0[dd]);
                    sacc[q][8 + dd] += cm * bf2f((ushort)h1[dd]);
                }
            }
        }
        #pragma unroll
        for (int off = 32; off >= 1; off >>= 1) {
            #pragma unroll
            for (int q = 0; q < 4; ++q)
                #pragma unroll
                for (int dd = 0; dd < 16; ++dd)
                    sacc[q][dd] += __shfl_xor(sacc[q][dd], off, 64);
        }
        #pragma unroll
        for (int q = 0; q < 4; ++q) {
            float s2 = 0.f;
            #pragma unroll
            for (int dd = 0; dd < 16; ++dd) s2 += sacc[q][dd] * sacc[q][dd];
            const float scale = s2 / (1.f + s2) / sqrtf(s2 + 1e-7f);
            #pragma unroll
            for (int dd = 0; dd < 16; ++dd) ov[q][dd] = scale * sacc[q][dd];
        }

        if (it < 2) {
            for (int r = 0; r < 8; ++r) {
                const int nn = r * 64 + lane;
                #pragma unroll
                for (int q = 0; q < 4; ++q) {
                    const int m = w * 4 + q;
                    const size_t base = (((size_t)b * M_ + m) * N_ + nn) * D_;
                    short8 h0 = *(const short8*)(hat + base);
                    short8 h1 = *(const short8*)(hat + base + 8);
                    float dot = 0.f;
                    #pragma unroll
                    for (int dd = 0; dd < 8; ++dd) {
                        dot += ov[q][dd]     * bf2f((ushort)h0[dd]);
                        dot += ov[q][8 + dd] * bf2f((ushort)h1[dd]);
                    }
                    blog[m][nn] += dot;
                }
            }
        }
        __syncthreads();
    }

    if (lane == 0) {
        #pragma unroll
        for (int q = 0; q < 4; ++q) {
            const int m = w * 4 + q;
            #pragma unroll
            for (int c4 = 0; c4 < 4; ++c4) {
                fl4 v;
                v[0] = ov[q][c4 * 4 + 0];
                v[1] = ov[q][c4 * 4 + 1];
                v[2] = ov[q][c4 * 4 + 2];
                v[3] = ov[q][c4 * 4 + 3];
                *(fl4*)&out[((size_t)b * M_ + m) * D_ + c4 * 4] = v;
            }
        }
    }
}

extern "C" void kernel_launch(void* const* d_in, const int* in_sizes, int n_in,
                              void* d_out, int out_size, void* d_ws, size_t ws_size,
                              hipStream_t stream) {
    const float* x = (const float*)d_in[0];        // [128, 512, 256] fp32
    const float* W = (const float*)d_in[1];        // [32, 512, 16, 256] fp32
    ushort* hat = (ushort*)d_ws;                   // bf16 [128,32,512,16] = 64 MB
    float* out = (float*)d_out;                    // fp32 [128,32,16]

    hat_gemm<<<dim3(N_), dim3(512), 0, stream>>>(x, W, hat);
    routing<<<dim3(B_), dim3(512), 0, stream>>>(hat, out);
}